// Round 5
// baseline (17583.060 us; speedup 1.0000x reference)
//
#include <hip/hip_runtime.h>

typedef __attribute__((ext_vector_type(8))) short short8;
typedef __attribute__((ext_vector_type(4))) float f32x4;

#define B_   128
#define T_   512
#define NE_  256
#define N_   1024
#define NA_  128
#define KFI  2304   /* NE + 2N */
#define KCU  1280   /* NE + N  */
#define BN   (B_ * N_)   /* 131072 */
#define TS   513         /* T + 1 h slots (slot 0 = zeros) */

/* workspace byte offsets, total 185,602,048 B */
#define OFF_WTFI   0UL
#define OFF_WTCU   9437184UL
#define OFF_WTH    12058624UL
#define OFF_WTOUT  16777216UL
#define OFF_XE     17039360UL
#define OFF_FLAGS  50593792UL   /* fP u32[8][64] | fQ u32[8][64] = 4 KiB */
#define OFF_CBF    50597888UL   /* 2 x B x N bf16 = 512 KiB */
#define OFF_STATES 51122176UL   /* 128 x 513 x 1024 bf16 h history / output */

__device__ __forceinline__ unsigned short f2bf(float v) {
  unsigned int u = __float_as_uint(v);
  unsigned int r = (u + 0x7fffu + ((u >> 16) & 1u)) >> 16;
  return (unsigned short)r;
}
__device__ __forceinline__ float sigm(float x) { return 1.f / (1.f + __expf(-x)); }
__device__ __forceinline__ float tanhfast(float x) { return 1.f - 2.f / (__expf(2.f * x) + 1.f); }

#define MFMA(a, b, c) __builtin_amdgcn_mfma_f32_16x16x32_bf16((a), (b), (c), 0, 0, 0)

/* 16B load that bypasses (possibly stale) L1/L2: two agent-scope relaxed
   atomic 8B loads (sc0 sc1) -> reads the IF coherence point. */
__device__ __forceinline__ short8 ld8_agent(const unsigned short* p) {
  union { unsigned long long q[2]; short8 v; } u;
  u.q[0] = __hip_atomic_load((unsigned long long*)p,     __ATOMIC_RELAXED, __HIP_MEMORY_SCOPE_AGENT);
  u.q[1] = __hip_atomic_load((unsigned long long*)p + 1, __ATOMIC_RELAXED, __HIP_MEMORY_SCOPE_AGENT);
  return u.v;
}

/* ---------------- weight transpose fp32(K x N) -> bf16(N x K) ---------------- */
__global__ void transpose_to_bf16(const float* __restrict__ src,
                                  unsigned short* __restrict__ dst,
                                  int K, int N) {
  __shared__ float tile[32][33];
  const int k0 = blockIdx.y * 32, n0 = blockIdx.x * 32;
  const int tx = threadIdx.x, ty = threadIdx.y;  /* block (32,8) */
#pragma unroll
  for (int i = 0; i < 32; i += 8)
    tile[ty + i][tx] = src[(size_t)(k0 + ty + i) * N + n0 + tx];
  __syncthreads();
#pragma unroll
  for (int i = 0; i < 32; i += 8)
    dst[(size_t)(n0 + ty + i) * K + k0 + tx] = f2bf(tile[tx][ty + i]);
}

/* ---------------- embedding gather ------------------------------------------ */
__global__ void embed_kernel(const int* __restrict__ x, const float* __restrict__ emb,
                             unsigned short* __restrict__ xe) {
  const int r = blockIdx.x;          /* r = t*128 + b */
  const int b = r & 127, t = r >> 7;
  const int e = threadIdx.x;
  const int a = x[b * T_ + t];
  xe[(size_t)r * NE_ + e] = f2bf(emb[(size_t)a * NE_ + e]);
}

/* ---------------- zero flags + cbf (sc1 stores) ----------------------------- */
__global__ void zero_sync_region(char* __restrict__ ws) {
  unsigned* p = (unsigned*)(ws + OFF_FLAGS);
  const int i = blockIdx.x * blockDim.x + threadIdx.x;
  if (i < (int)((OFF_STATES - OFF_FLAGS) / 4))
    __hip_atomic_store(p + i, 0u, __ATOMIC_RELAXED, __HIP_MEMORY_SCOPE_AGENT);
}

/* ---------------- zero h slot 0 for each batch row -------------------------- */
__global__ void zero_h0(char* __restrict__ ws) {
  unsigned* st = (unsigned*)(ws + OFF_STATES);
  unsigned* row = st + (size_t)blockIdx.x * TS * 512;  /* u32 units: 512/row */
  __hip_atomic_store(row + threadIdx.x,       0u, __ATOMIC_RELAXED, __HIP_MEMORY_SCOPE_AGENT);
  __hip_atomic_store(row + 256 + threadIdx.x, 0u, __ATOMIC_RELAXED, __HIP_MEMORY_SCOPE_AGENT);
}

/* ---------------- persistent recurrent kernel ------------------------------- */
/* 256 blocks x 256 threads. Batch = 8 independent 16-row LSTM groups.
   blk bits: [2:0]=xcd, [4:3]=slot, [7:5]=nh; ni = xcd*8+nh (16-col tile),
   groups gA=slot, gB=slot+4 run phase-shifted (P_A P_B Q_A Q_B per step) so
   each group's IF publish->detect leg hides behind the other group's phase.
   The 4 slots of one ni share the same XCD -> weight slice L2-resident.
   Weights loaded per-use from L2 (NO register residency, NO launch_bounds
   min-waves: both reverted after R4's silent launch failure).
   Sync: per-group 64 block-flags; publish = sc1 stores + s_waitcnt + flag;
   wait = wave0 polls 64 flags (agent loads), syncthreads.
   Flag-independent MFMA chunks issue before each wait. */
__global__ void __launch_bounds__(256) lstm_persistent(
    char* __restrict__ ws,
    const float* __restrict__ b_fi,
    const float* __restrict__ b_cu,
    const float* __restrict__ b_h) {
  const unsigned short* Wt_fi = (const unsigned short*)(ws + OFF_WTFI);
  const unsigned short* Wt_cu = (const unsigned short*)(ws + OFF_WTCU);
  const unsigned short* Wt_h  = (const unsigned short*)(ws + OFF_WTH);
  const unsigned short* xe    = (const unsigned short*)(ws + OFF_XE);
  unsigned short* cbf    = (unsigned short*)(ws + OFF_CBF);
  unsigned*       cbf32  = (unsigned*)(ws + OFF_CBF);
  unsigned short* states = (unsigned short*)(ws + OFF_STATES);
  unsigned*       states32 = (unsigned*)(ws + OFF_STATES);
  unsigned* fP = (unsigned*)(ws + OFF_FLAGS);
  unsigned* fQ = fP + 512;

  const int blk  = blockIdx.x;
  const int xcd  = blk & 7;
  const int slot = (blk >> 3) & 3;
  const int nh   = blk >> 5;
  const int ni   = xcd * 8 + nh;     /* 0..63 col tile */
  const int gA   = slot, gB = slot + 4;
  const int tid  = threadIdx.x;
  const int wave = tid >> 6;
  const int lane = tid & 63;
  const int l15  = lane & 15;
  const int quad = lane >> 4;
  const int qo   = quad * 8;
  const int n0   = ni * 16;

  const unsigned short* bfp = Wt_fi + (size_t)(n0 + l15) * KFI;
  const unsigned short* bip = Wt_fi + (size_t)(N_ + n0 + l15) * KFI;
  const unsigned short* bup = Wt_cu + (size_t)(n0 + l15) * KCU;
  const unsigned short* bhp = Wt_h  + (size_t)(n0 + l15) * KFI;

  __shared__ float red[4][3][4][72];  /* padded: kills R3's 3.4e7 conflicts */
  __shared__ float sb[4][16];         /* biases f,i,u,h for 16 cols */
  if (tid < 64) {
    const int g = tid >> 4, col = tid & 15;
    float v;
    if      (g == 0) v = b_fi[n0 + col];
    else if (g == 1) v = b_fi[N_ + n0 + col];
    else if (g == 2) v = b_cu[n0 + col];
    else             v = b_h[n0 + col];
    sb[g][col] = v;
  }

  /* elementwise: tid<128 -> (row in 16, col pair); 2 elems/thread */
  const int erow = tid >> 3;          /* 0..31, valid rows 0..15 for tid<128 */
  const int colp = tid & 7;
  const int ereg = erow & 3;
  const int lbas = (erow >> 2) * 16 + colp * 2;

  float cA[2] = {0.f, 0.f}, cB[2] = {0.f, 0.f};  /* c state in registers */

  auto phaseP = [&](const int g, const int t, float* cv) {
    const int cur = t & 1, prv = cur ^ 1;
    const unsigned short* xr = xe + ((size_t)t * B_ + g * 16 + l15) * NE_;
    const unsigned short* hr = states + ((size_t)(g * 16 + l15) * TS + t) * N_;
    const unsigned short* cr = cbf + (size_t)prv * BN + (size_t)(g * 16 + l15) * N_;
    f32x4 fa = {0.f,0.f,0.f,0.f}, ia = {0.f,0.f,0.f,0.f}, ua = {0.f,0.f,0.f,0.f};
    /* pre-wait: x-part + c(t-1)-part (visible via previous-step waits) */
#pragma unroll
    for (int c = 0; c < 2; ++c) {
      const int k = (wave + 4 * c) * 32;
      short8 a = *(const short8*)(xr + k + qo);
      fa = MFMA(a, *(const short8*)(bfp + k + qo), fa);
      ia = MFMA(a, *(const short8*)(bip + k + qo), ia);
      ua = MFMA(a, *(const short8*)(bup + k + qo), ua);
    }
#pragma unroll
    for (int c = 10; c < 18; ++c) {
      const int k = (wave + 4 * c) * 32;
      short8 a = ld8_agent(cr + (k - KCU) + qo);
      fa = MFMA(a, *(const short8*)(bfp + k + qo), fa);
      ia = MFMA(a, *(const short8*)(bip + k + qo), ia);
    }
    /* wait: h(t-1) published by all 64 blocks of group g */
    if (wave == 0) {
      while (__hip_atomic_load(fQ + g * 64 + lane, __ATOMIC_RELAXED,
                               __HIP_MEMORY_SCOPE_AGENT) < (unsigned)t) { }
    }
    __syncthreads();
#pragma unroll
    for (int c = 2; c < 10; ++c) {
      const int k = (wave + 4 * c) * 32;
      short8 a = __builtin_nontemporal_load((const short8*)(hr + (k - NE_) + qo));
      fa = MFMA(a, *(const short8*)(bfp + k + qo), fa);
      ia = MFMA(a, *(const short8*)(bip + k + qo), ia);
      ua = MFMA(a, *(const short8*)(bup + k + qo), ua);
    }
#pragma unroll
    for (int r = 0; r < 4; ++r) {
      red[wave][0][r][lane] = fa[r];
      red[wave][1][r][lane] = ia[r];
      red[wave][2][r][lane] = ua[r];
    }
    __syncthreads();
    if (tid < 128) {
      unsigned pack = 0;
#pragma unroll
      for (int j = 0; j < 2; ++j) {
        const int L = lbas + j;
        const float fv = red[0][0][ereg][L] + red[1][0][ereg][L] +
                         red[2][0][ereg][L] + red[3][0][ereg][L] + sb[0][colp * 2 + j];
        const float iv = red[0][1][ereg][L] + red[1][1][ereg][L] +
                         red[2][1][ereg][L] + red[3][1][ereg][L] + sb[1][colp * 2 + j];
        const float uv = red[0][2][ereg][L] + red[1][2][ereg][L] +
                         red[2][2][ereg][L] + red[3][2][ereg][L] + sb[2][colp * 2 + j];
        const float c2 = sigm(fv) * cv[j] + sigm(iv) * tanhfast(uv);
        cv[j] = c2;
        pack |= (unsigned)f2bf(c2) << (16 * j);
      }
      unsigned* p = cbf32 +
          (((size_t)cur * BN + (size_t)(g * 16 + erow) * N_ + n0 + colp * 2) >> 1);
      __hip_atomic_store(p, pack, __ATOMIC_RELAXED, __HIP_MEMORY_SCOPE_AGENT);
    }
    __builtin_amdgcn_s_waitcnt(0);
    __syncthreads();
    if (tid == 0)
      __hip_atomic_store(fP + g * 64 + ni, (unsigned)(t + 1), __ATOMIC_RELAXED,
                         __HIP_MEMORY_SCOPE_AGENT);
  };

  auto phaseQ = [&](const int g, const int t, const float* cv) {
    const int cur = t & 1;
    const unsigned short* xr = xe + ((size_t)t * B_ + g * 16 + l15) * NE_;
    const unsigned short* hr = states + ((size_t)(g * 16 + l15) * TS + t) * N_;
    const unsigned short* c2r = cbf + (size_t)cur * BN + (size_t)(g * 16 + l15) * N_;
    f32x4 ha = {0.f,0.f,0.f,0.f};
    /* pre-wait: x + h(t-1) (flagged by this step's P-wait already) */
#pragma unroll
    for (int c = 0; c < 2; ++c) {
      const int k = (wave + 4 * c) * 32;
      short8 a = *(const short8*)(xr + k + qo);
      ha = MFMA(a, *(const short8*)(bhp + k + qo), ha);
    }
#pragma unroll
    for (int c = 2; c < 10; ++c) {
      const int k = (wave + 4 * c) * 32;
      short8 a = __builtin_nontemporal_load((const short8*)(hr + (k - NE_) + qo));
      ha = MFMA(a, *(const short8*)(bhp + k + qo), ha);
    }
    /* wait: c2(t) published by all 64 blocks of group g */
    if (wave == 0) {
      while (__hip_atomic_load(fP + g * 64 + lane, __ATOMIC_RELAXED,
                               __HIP_MEMORY_SCOPE_AGENT) < (unsigned)(t + 1)) { }
    }
    __syncthreads();
#pragma unroll
    for (int c = 10; c < 18; ++c) {
      const int k = (wave + 4 * c) * 32;
      short8 a = ld8_agent(c2r + (k - KCU) + qo);
      ha = MFMA(a, *(const short8*)(bhp + k + qo), ha);
    }
#pragma unroll
    for (int r = 0; r < 4; ++r)
      red[wave][0][r][lane] = ha[r];
    __syncthreads();
    if (tid < 128) {
      unsigned pack = 0;
#pragma unroll
      for (int j = 0; j < 2; ++j) {
        const int L = lbas + j;
        const float hv = red[0][0][ereg][L] + red[1][0][ereg][L] +
                         red[2][0][ereg][L] + red[3][0][ereg][L] + sb[3][colp * 2 + j];
        pack |= (unsigned)f2bf(hv * tanhfast(cv[j])) << (16 * j);
      }
      unsigned* p = states32 +
          ((((size_t)(g * 16 + erow) * TS + (t + 1)) * N_ + n0 + colp * 2) >> 1);
      __hip_atomic_store(p, pack, __ATOMIC_RELAXED, __HIP_MEMORY_SCOPE_AGENT);
    }
    __builtin_amdgcn_s_waitcnt(0);
    __syncthreads();
    if (tid == 0)
      __hip_atomic_store(fQ + g * 64 + ni, (unsigned)(t + 1), __ATOMIC_RELAXED,
                         __HIP_MEMORY_SCOPE_AGENT);
  };

  for (int t = 0; t < T_; ++t) {
    phaseP(gA, t, cA);
    phaseP(gB, t, cB);
    phaseQ(gA, t, cA);
    phaseQ(gB, t, cB);
  }
}

/* ---------------- epilogue: y = states @ W_out + b_out ---------------------- */
__global__ void __launch_bounds__(256) out_gemm(const char* __restrict__ ws,
                                                const float* __restrict__ b_out,
                                                float* __restrict__ y) {
  const unsigned short* states = (const unsigned short*)(ws + OFF_STATES);
  const unsigned short* Wt_out = (const unsigned short*)(ws + OFF_WTOUT);
  const int tid = threadIdx.x, wave = tid >> 6, lane = tid & 63;
  const int l15 = lane & 15, quad = lane >> 4, qo = quad * 8;
  const int msub = wave & 1, npair = wave >> 1;
  const size_t r0 = (size_t)blockIdx.x * 32;  /* 32 consecutive t, same batch m */
  const size_t mb = r0 >> 9;
  const unsigned short* arow =
      states + (mb * TS + (r0 & 511) + msub * 16 + l15 + 1) * N_;
  const unsigned short* b0p = Wt_out + (size_t)(npair * 64 + 0  + l15) * N_;
  const unsigned short* b1p = Wt_out + (size_t)(npair * 64 + 16 + l15) * N_;
  const unsigned short* b2p = Wt_out + (size_t)(npair * 64 + 32 + l15) * N_;
  const unsigned short* b3p = Wt_out + (size_t)(npair * 64 + 48 + l15) * N_;
  f32x4 a0 = {0.f,0.f,0.f,0.f}, a1 = {0.f,0.f,0.f,0.f};
  f32x4 a2 = {0.f,0.f,0.f,0.f}, a3 = {0.f,0.f,0.f,0.f};
#pragma unroll 8
  for (int c = 0; c < 32; ++c) {
    const int k = c * 32;
    short8 av = *(const short8*)(arow + k + qo);
    a0 = MFMA(av, *(const short8*)(b0p + k + qo), a0);
    a1 = MFMA(av, *(const short8*)(b1p + k + qo), a1);
    a2 = MFMA(av, *(const short8*)(b2p + k + qo), a2);
    a3 = MFMA(av, *(const short8*)(b3p + k + qo), a3);
  }
#pragma unroll
  for (int r = 0; r < 4; ++r) {
    const size_t m = r0 + msub * 16 + quad * 4 + r;
    y[m * NA_ + npair * 64 + 0  + l15] = a0[r] + b_out[npair * 64 + 0  + l15];
    y[m * NA_ + npair * 64 + 16 + l15] = a1[r] + b_out[npair * 64 + 16 + l15];
    y[m * NA_ + npair * 64 + 32 + l15] = a2[r] + b_out[npair * 64 + 32 + l15];
    y[m * NA_ + npair * 64 + 48 + l15] = a3[r] + b_out[npair * 64 + 48 + l15];
  }
}

/* ---------------- host ------------------------------------------------------ */
extern "C" void kernel_launch(void* const* d_in, const int* in_sizes, int n_in,
                              void* d_out, int out_size, void* d_ws, size_t ws_size,
                              hipStream_t stream) {
  const int*   x     = (const int*)d_in[0];
  const float* emb   = (const float*)d_in[1];
  const float* W_fi  = (const float*)d_in[2];
  const float* b_fi  = (const float*)d_in[3];
  const float* W_cu  = (const float*)d_in[4];
  const float* b_cu  = (const float*)d_in[5];
  const float* W_h   = (const float*)d_in[6];
  const float* b_h   = (const float*)d_in[7];
  const float* W_out = (const float*)d_in[8];
  const float* b_out = (const float*)d_in[9];
  char* ws = (char*)d_ws;
  float* y = (float*)d_out;
  (void)in_sizes; (void)n_in; (void)out_size; (void)ws_size; /* needs ~186 MB ws */

  transpose_to_bf16<<<dim3(2048 / 32, 2304 / 32), dim3(32, 8), 0, stream>>>(
      W_fi, (unsigned short*)(ws + OFF_WTFI), KFI, 2048);
  transpose_to_bf16<<<dim3(1024 / 32, 1280 / 32), dim3(32, 8), 0, stream>>>(
      W_cu, (unsigned short*)(ws + OFF_WTCU), KCU, 1024);
  transpose_to_bf16<<<dim3(1024 / 32, 2304 / 32), dim3(32, 8), 0, stream>>>(
      W_h, (unsigned short*)(ws + OFF_WTH), KFI, 1024);
  transpose_to_bf16<<<dim3(128 / 32, 1024 / 32), dim3(32, 8), 0, stream>>>(
      W_out, (unsigned short*)(ws + OFF_WTOUT), N_, 128);

  embed_kernel<<<T_ * B_, NE_, 0, stream>>>(x, emb, (unsigned short*)(ws + OFF_XE));

  zero_sync_region<<<516, 256, 0, stream>>>(ws);  /* flags + cbf */
  zero_h0<<<128, 256, 0, stream>>>(ws);           /* h slot 0 per batch row */

  char* wsp = ws;
  void* kargs[4] = { (void*)&wsp, (void*)&b_fi, (void*)&b_cu, (void*)&b_h };
  hipLaunchCooperativeKernel((void*)lstm_persistent, dim3(256), dim3(256),
                             kargs, 0, stream);

  out_gemm<<<(B_ * T_) / 32, 256, 0, stream>>>(ws, b_out, y);
}

// Round 6
// 8543.414 us; speedup vs baseline: 2.0581x; 2.0581x over previous
//
#include <hip/hip_runtime.h>

typedef __attribute__((ext_vector_type(8))) short short8;
typedef __attribute__((ext_vector_type(4))) float f32x4;

#define B_   128
#define T_   512
#define NE_  256
#define N_   1024
#define NA_  128
#define KFI  2304   /* NE + 2N */
#define KCU  1280   /* NE + N  */
#define BN   (B_ * N_)   /* 131072 */
#define TS   513         /* T + 1 h slots (slot 0 = zeros) */

/* workspace byte offsets, total ~186 MB */
#define OFF_WTFI   0UL
#define OFF_WTCU   9437184UL
#define OFF_WTH    12058624UL
#define OFF_WTOUT  16777216UL
#define OFF_XE     17039360UL
#define OFF_FLAGS  50593792UL   /* aP u32[4][64] | aQ u32[4][64] = 2 KiB */
#define OFF_CBF    50595840UL   /* 2 x B x N bf16 = 512 KiB */
#define OFF_STATES 51122176UL   /* 128 x 513 x 1024 bf16 h history / output */

__device__ __forceinline__ unsigned short f2bf(float v) {
  unsigned int u = __float_as_uint(v);
  unsigned int r = (u + 0x7fffu + ((u >> 16) & 1u)) >> 16;
  return (unsigned short)r;
}
__device__ __forceinline__ float sigm(float x) { return 1.f / (1.f + __expf(-x)); }
__device__ __forceinline__ float tanhfast(float x) { return 1.f - 2.f / (__expf(2.f * x) + 1.f); }

#define MFMA(a, b, c) __builtin_amdgcn_mfma_f32_16x16x32_bf16((a), (b), (c), 0, 0, 0)

/* 16B load bypassing (possibly stale) L1/L2: two agent-scope relaxed atomic
   8B loads -> reads the IF coherence point. Used ONLY for the ping-pong c2
   buffer (reused addresses). h/x use normal loads (fresh-per-t addresses). */
__device__ __forceinline__ short8 ld8_agent(const unsigned short* p) {
  union { unsigned long long q[2]; short8 v; } u;
  u.q[0] = __hip_atomic_load((unsigned long long*)p,     __ATOMIC_RELAXED, __HIP_MEMORY_SCOPE_AGENT);
  u.q[1] = __hip_atomic_load((unsigned long long*)p + 1, __ATOMIC_RELAXED, __HIP_MEMORY_SCOPE_AGENT);
  return u.v;
}

/* ---------------- weight transpose fp32(K x N) -> bf16(N x K) ---------------- */
__global__ void transpose_to_bf16(const float* __restrict__ src,
                                  unsigned short* __restrict__ dst,
                                  int K, int N) {
  __shared__ float tile[32][33];
  const int k0 = blockIdx.y * 32, n0 = blockIdx.x * 32;
  const int tx = threadIdx.x, ty = threadIdx.y;  /* block (32,8) */
#pragma unroll
  for (int i = 0; i < 32; i += 8)
    tile[ty + i][tx] = src[(size_t)(k0 + ty + i) * N + n0 + tx];
  __syncthreads();
#pragma unroll
  for (int i = 0; i < 32; i += 8)
    dst[(size_t)(n0 + ty + i) * K + k0 + tx] = f2bf(tile[tx][ty + i]);
}

/* ---------------- embedding gather ------------------------------------------ */
__global__ void embed_kernel(const int* __restrict__ x, const float* __restrict__ emb,
                             unsigned short* __restrict__ xe) {
  const int r = blockIdx.x;          /* r = t*128 + b */
  const int b = r & 127, t = r >> 7;
  const int e = threadIdx.x;
  const int a = x[b * T_ + t];
  xe[(size_t)r * NE_ + e] = f2bf(emb[(size_t)a * NE_ + e]);
}

/* ---------------- zero flags + cbf (sc1 stores) ----------------------------- */
__global__ void zero_sync_region(char* __restrict__ ws) {
  unsigned* p = (unsigned*)(ws + OFF_FLAGS);
  const int i = blockIdx.x * blockDim.x + threadIdx.x;
  if (i < (int)((OFF_STATES - OFF_FLAGS) / 4))
    __hip_atomic_store(p + i, 0u, __ATOMIC_RELAXED, __HIP_MEMORY_SCOPE_AGENT);
}

/* ---------------- zero h slot 0 for each batch row -------------------------- */
__global__ void zero_h0(char* __restrict__ ws) {
  unsigned* st = (unsigned*)(ws + OFF_STATES);
  unsigned* row = st + (size_t)blockIdx.x * TS * 512;  /* u32 units: 512/row */
  __hip_atomic_store(row + threadIdx.x,       0u, __ATOMIC_RELAXED, __HIP_MEMORY_SCOPE_AGENT);
  __hip_atomic_store(row + 256 + threadIdx.x, 0u, __ATOMIC_RELAXED, __HIP_MEMORY_SCOPE_AGENT);
}

/* ---------------- persistent recurrent kernel ------------------------------- */
/* 256 blocks x 256 threads. Batch = 4 independent 32-row LSTM groups, 64
   col-tile blocks each (R3 shape). blk: [2:0]=xcd, [4:3]... slot=blk>>3,
   nh=slot>>2, mi=slot&3, ni=xcd*8+nh -> the 4 mi of one ni share an XCD
   (weight slice L2-resident). 4 waves split K into interleaved 32-chunks.
   R6 deltas vs R3:
     - Q's c2-chunk reads feed BOTH hg(t) and next step's f/i c-partials
       (register-carried) -> P has no c-reads, c IF traffic halved.
     - x/h A-frags register-carried from P to Q -> Q pre-wait pass is
       load-free.
     - h reads are NORMAL loads (fresh address per t -> never stale; L2
       amortizes the fill across the XCD's 8 same-group blocks).
   Sync: per-group 64 block-flags; publish = sc1 stores + s_waitcnt + flag;
   wait = wave0 polls 64 flags coalesced, __all, syncthreads. */
__global__ void __launch_bounds__(256) lstm_persistent(
    char* __restrict__ ws,
    const float* __restrict__ b_fi,
    const float* __restrict__ b_cu,
    const float* __restrict__ b_h) {
  const unsigned short* Wt_fi = (const unsigned short*)(ws + OFF_WTFI);
  const unsigned short* Wt_cu = (const unsigned short*)(ws + OFF_WTCU);
  const unsigned short* Wt_h  = (const unsigned short*)(ws + OFF_WTH);
  const unsigned short* xe    = (const unsigned short*)(ws + OFF_XE);
  unsigned short* cbf    = (unsigned short*)(ws + OFF_CBF);
  unsigned*       cbf32  = (unsigned*)(ws + OFF_CBF);
  unsigned short* states = (unsigned short*)(ws + OFF_STATES);
  unsigned*       states32 = (unsigned*)(ws + OFF_STATES);
  unsigned* aP = (unsigned*)(ws + OFF_FLAGS);
  unsigned* aQ = aP + 256;

  const int blk  = blockIdx.x;
  const int xcd  = blk & 7;
  const int slot = blk >> 3;
  const int nh   = slot >> 2;
  const int mi   = slot & 3;               /* group 0..3 (32 batch rows) */
  const int ni   = xcd * 8 + nh;           /* col tile 0..63 */
  const int tid  = threadIdx.x;
  const int wave = tid >> 6;
  const int lane = tid & 63;
  const int l15  = lane & 15;
  const int quad = lane >> 4;
  const int qo   = quad * 8;
  const int n0   = ni * 16;
  const int mA0  = mi * 32 + l15;          /* A rows, halves 0/1 */
  const int mA1  = mA0 + 16;

  const unsigned short* bfp = Wt_fi + (size_t)(n0 + l15) * KFI;
  const unsigned short* bip = Wt_fi + (size_t)(N_ + n0 + l15) * KFI;
  const unsigned short* bup = Wt_cu + (size_t)(n0 + l15) * KCU;
  const unsigned short* bhp = Wt_h  + (size_t)(n0 + l15) * KFI;

  __shared__ float red[4][6][4][72];  /* [wave][acc][reg][lane(+pad)] */
  __shared__ float sb[4][16];         /* biases f,i,u,h for 16 cols */
  if (tid < 64) {
    const int g = tid >> 4, col = tid & 15;
    float v;
    if      (g == 0) v = b_fi[n0 + col];
    else if (g == 1) v = b_fi[N_ + n0 + col];
    else if (g == 2) v = b_cu[n0 + col];
    else             v = b_h[n0 + col];
    sb[g][col] = v;
  }

  /* elementwise: tid -> (half hh, row-in-16 erow, col pair colp); 2 elems */
  const int hh   = tid >> 7;
  const int erow = (tid >> 3) & 15;
  const int colp = tid & 7;
  const int ereg = erow & 3;
  const int lbas = (erow >> 2) * 16 + colp * 2;
  const int brow = mi * 32 + hh * 16 + erow;       /* global batch row */

  float creg[2] = {0.f, 0.f};                      /* c state (2 cols) */
  f32x4 fc0 = {0,0,0,0}, fc1 = {0,0,0,0};          /* carried c-part partials */
  f32x4 ic0 = {0,0,0,0}, ic1 = {0,0,0,0};

  for (int t = 0; t < T_; ++t) {
    const int cur = t & 1;
    const unsigned short* xr0 = xe + ((size_t)t * B_ + mA0) * NE_;
    const unsigned short* xr1 = xe + ((size_t)t * B_ + mA1) * NE_;
    const unsigned short* hr0 = states + ((size_t)mA0 * TS + t) * N_; /* h(t-1) */
    const unsigned short* hr1 = states + ((size_t)mA1 * TS + t) * N_;

    /* ---------------- Phase P: f,i,u -> c2 ---------------- */
    f32x4 f0 = fc0, f1 = fc1, i0 = ic0, i1 = ic1;  /* start from c-partials */
    f32x4 u0 = {0,0,0,0}, u1 = {0,0,0,0};
    short8 ax0[2], ax1[2], axh0[8], axh1[8];       /* register A-frag cache */
#pragma unroll
    for (int c = 0; c < 2; ++c) {                  /* x-part, pre-wait */
      const int k = (wave + 4 * c) * 32;
      ax0[c] = *(const short8*)(xr0 + k + qo);
      ax1[c] = *(const short8*)(xr1 + k + qo);
      short8 bf = *(const short8*)(bfp + k + qo);
      short8 bi = *(const short8*)(bip + k + qo);
      short8 bu = *(const short8*)(bup + k + qo);
      f0 = MFMA(ax0[c], bf, f0);  f1 = MFMA(ax1[c], bf, f1);
      i0 = MFMA(ax0[c], bi, i0);  i1 = MFMA(ax1[c], bi, i1);
      u0 = MFMA(ax0[c], bu, u0);  u1 = MFMA(ax1[c], bu, u1);
    }
    /* wait: h(t-1) published by all 64 blocks of group mi */
    if (wave == 0) {
      while (!__all((int)(__hip_atomic_load(aQ + mi * 64 + lane, __ATOMIC_RELAXED,
                                            __HIP_MEMORY_SCOPE_AGENT) >= (unsigned)t))) { }
    }
    __syncthreads();
#pragma unroll
    for (int c = 0; c < 8; ++c) {                  /* h-part, normal loads */
      const int k = (wave + 4 * (c + 2)) * 32;     /* 256..2303 range */
      const int kh = k - NE_;
      axh0[c] = *(const short8*)(hr0 + kh + qo);
      axh1[c] = *(const short8*)(hr1 + kh + qo);
      short8 bf = *(const short8*)(bfp + k + qo);
      short8 bi = *(const short8*)(bip + k + qo);
      short8 bu = *(const short8*)(bup + k + qo);
      f0 = MFMA(axh0[c], bf, f0);  f1 = MFMA(axh1[c], bf, f1);
      i0 = MFMA(axh0[c], bi, i0);  i1 = MFMA(axh1[c], bi, i1);
      u0 = MFMA(axh0[c], bu, u0);  u1 = MFMA(axh1[c], bu, u1);
    }
#pragma unroll
    for (int r = 0; r < 4; ++r) {
      red[wave][0][r][lane] = f0[r];  red[wave][1][r][lane] = f1[r];
      red[wave][2][r][lane] = i0[r];  red[wave][3][r][lane] = i1[r];
      red[wave][4][r][lane] = u0[r];  red[wave][5][r][lane] = u1[r];
    }
    __syncthreads();
    {
      unsigned pack = 0;
#pragma unroll
      for (int j = 0; j < 2; ++j) {
        const int L = lbas + j;
        const float fv = red[0][hh][ereg][L] + red[1][hh][ereg][L] +
                         red[2][hh][ereg][L] + red[3][hh][ereg][L] + sb[0][colp * 2 + j];
        const float iv = red[0][2+hh][ereg][L] + red[1][2+hh][ereg][L] +
                         red[2][2+hh][ereg][L] + red[3][2+hh][ereg][L] + sb[1][colp * 2 + j];
        const float uv = red[0][4+hh][ereg][L] + red[1][4+hh][ereg][L] +
                         red[2][4+hh][ereg][L] + red[3][4+hh][ereg][L] + sb[2][colp * 2 + j];
        const float c2 = sigm(fv) * creg[j] + sigm(iv) * tanhfast(uv);
        creg[j] = c2;
        pack |= (unsigned)f2bf(c2) << (16 * j);
      }
      unsigned* p = cbf32 +
          (((size_t)cur * BN + (size_t)brow * N_ + n0 + colp * 2) >> 1);
      __hip_atomic_store(p, pack, __ATOMIC_RELAXED, __HIP_MEMORY_SCOPE_AGENT);
    }
    __builtin_amdgcn_s_waitcnt(0);
    __syncthreads();
    if (tid == 0)
      __hip_atomic_store(aP + mi * 64 + ni, (unsigned)(t + 1), __ATOMIC_RELAXED,
                         __HIP_MEMORY_SCOPE_AGENT);

    /* ---------------- Phase Q: hg -> h2 (+ next-step f/i c-partials) -------- */
    f32x4 h0 = {0,0,0,0}, h1 = {0,0,0,0};
    f32x4 fn0 = {0,0,0,0}, fn1 = {0,0,0,0}, in0 = {0,0,0,0}, in1 = {0,0,0,0};
#pragma unroll
    for (int c = 0; c < 2; ++c) {                  /* x-part from registers */
      const int k = (wave + 4 * c) * 32;
      short8 bh = *(const short8*)(bhp + k + qo);
      h0 = MFMA(ax0[c], bh, h0);  h1 = MFMA(ax1[c], bh, h1);
    }
#pragma unroll
    for (int c = 0; c < 8; ++c) {                  /* h-part from registers */
      const int k = (wave + 4 * (c + 2)) * 32;
      short8 bh = *(const short8*)(bhp + k + qo);
      h0 = MFMA(axh0[c], bh, h0);  h1 = MFMA(axh1[c], bh, h1);
    }
    /* wait: c2(t) published by all 64 blocks of group mi */
    if (wave == 0) {
      while (!__all((int)(__hip_atomic_load(aP + mi * 64 + lane, __ATOMIC_RELAXED,
                                            __HIP_MEMORY_SCOPE_AGENT) >= (unsigned)(t + 1)))) { }
    }
    __syncthreads();
    const unsigned short* c2r0 = cbf + (size_t)cur * BN + (size_t)mA0 * N_;
    const unsigned short* c2r1 = cbf + (size_t)cur * BN + (size_t)mA1 * N_;
#pragma unroll
    for (int c = 0; c < 8; ++c) {                  /* c2-part: hg AND f/i(t+1) */
      const int k = (wave + 4 * (c + 10)) * 32;    /* 1280..2303 */
      const int kc = k - KCU;
      short8 ca0 = ld8_agent(c2r0 + kc + qo);
      short8 ca1 = ld8_agent(c2r1 + kc + qo);
      short8 bh = *(const short8*)(bhp + k + qo);
      short8 bf = *(const short8*)(bfp + k + qo);
      short8 bi = *(const short8*)(bip + k + qo);
      h0  = MFMA(ca0, bh, h0);   h1  = MFMA(ca1, bh, h1);
      fn0 = MFMA(ca0, bf, fn0);  fn1 = MFMA(ca1, bf, fn1);
      in0 = MFMA(ca0, bi, in0);  in1 = MFMA(ca1, bi, in1);
    }
#pragma unroll
    for (int r = 0; r < 4; ++r) {
      red[wave][0][r][lane] = h0[r];
      red[wave][1][r][lane] = h1[r];
    }
    __syncthreads();
    {
      unsigned pack = 0;
#pragma unroll
      for (int j = 0; j < 2; ++j) {
        const int L = lbas + j;
        const float hv = red[0][hh][ereg][L] + red[1][hh][ereg][L] +
                         red[2][hh][ereg][L] + red[3][hh][ereg][L] + sb[3][colp * 2 + j];
        pack |= (unsigned)f2bf(hv * tanhfast(creg[j])) << (16 * j);
      }
      unsigned* p = states32 +
          ((((size_t)brow * TS + (t + 1)) * N_ + n0 + colp * 2) >> 1);
      __hip_atomic_store(p, pack, __ATOMIC_RELAXED, __HIP_MEMORY_SCOPE_AGENT);
    }
    __builtin_amdgcn_s_waitcnt(0);
    __syncthreads();
    if (tid == 0)
      __hip_atomic_store(aQ + mi * 64 + ni, (unsigned)(t + 1), __ATOMIC_RELAXED,
                         __HIP_MEMORY_SCOPE_AGENT);

    fc0 = fn0; fc1 = fn1; ic0 = in0; ic1 = in1;    /* carry to P(t+1) */
  }
}

/* ---------------- epilogue: y = states @ W_out + b_out ---------------------- */
__global__ void __launch_bounds__(256) out_gemm(const char* __restrict__ ws,
                                                const float* __restrict__ b_out,
                                                float* __restrict__ y) {
  const unsigned short* states = (const unsigned short*)(ws + OFF_STATES);
  const unsigned short* Wt_out = (const unsigned short*)(ws + OFF_WTOUT);
  const int tid = threadIdx.x, wave = tid >> 6, lane = tid & 63;
  const int l15 = lane & 15, quad = lane >> 4, qo = quad * 8;
  const int msub = wave & 1, npair = wave >> 1;
  const size_t r0 = (size_t)blockIdx.x * 32;  /* 32 consecutive t, same batch m */
  const size_t mb = r0 >> 9;
  const unsigned short* arow =
      states + (mb * TS + (r0 & 511) + msub * 16 + l15 + 1) * N_;
  const unsigned short* b0p = Wt_out + (size_t)(npair * 64 + 0  + l15) * N_;
  const unsigned short* b1p = Wt_out + (size_t)(npair * 64 + 16 + l15) * N_;
  const unsigned short* b2p = Wt_out + (size_t)(npair * 64 + 32 + l15) * N_;
  const unsigned short* b3p = Wt_out + (size_t)(npair * 64 + 48 + l15) * N_;
  f32x4 a0 = {0.f,0.f,0.f,0.f}, a1 = {0.f,0.f,0.f,0.f};
  f32x4 a2 = {0.f,0.f,0.f,0.f}, a3 = {0.f,0.f,0.f,0.f};
#pragma unroll 8
  for (int c = 0; c < 32; ++c) {
    const int k = c * 32;
    short8 av = *(const short8*)(arow + k + qo);
    a0 = MFMA(av, *(const short8*)(b0p + k + qo), a0);
    a1 = MFMA(av, *(const short8*)(b1p + k + qo), a1);
    a2 = MFMA(av, *(const short8*)(b2p + k + qo), a2);
    a3 = MFMA(av, *(const short8*)(b3p + k + qo), a3);
  }
#pragma unroll
  for (int r = 0; r < 4; ++r) {
    const size_t m = r0 + msub * 16 + quad * 4 + r;
    y[m * NA_ + npair * 64 + 0  + l15] = a0[r] + b_out[npair * 64 + 0  + l15];
    y[m * NA_ + npair * 64 + 16 + l15] = a1[r] + b_out[npair * 64 + 16 + l15];
    y[m * NA_ + npair * 64 + 32 + l15] = a2[r] + b_out[npair * 64 + 32 + l15];
    y[m * NA_ + npair * 64 + 48 + l15] = a3[r] + b_out[npair * 64 + 48 + l15];
  }
}

/* ---------------- host ------------------------------------------------------ */
extern "C" void kernel_launch(void* const* d_in, const int* in_sizes, int n_in,
                              void* d_out, int out_size, void* d_ws, size_t ws_size,
                              hipStream_t stream) {
  const int*   x     = (const int*)d_in[0];
  const float* emb   = (const float*)d_in[1];
  const float* W_fi  = (const float*)d_in[2];
  const float* b_fi  = (const float*)d_in[3];
  const float* W_cu  = (const float*)d_in[4];
  const float* b_cu  = (const float*)d_in[5];
  const float* W_h   = (const float*)d_in[6];
  const float* b_h   = (const float*)d_in[7];
  const float* W_out = (const float*)d_in[8];
  const float* b_out = (const float*)d_in[9];
  char* ws = (char*)d_ws;
  float* y = (float*)d_out;
  (void)in_sizes; (void)n_in; (void)out_size; (void)ws_size; /* needs ~186 MB ws */

  transpose_to_bf16<<<dim3(2048 / 32, 2304 / 32), dim3(32, 8), 0, stream>>>(
      W_fi, (unsigned short*)(ws + OFF_WTFI), KFI, 2048);
  transpose_to_bf16<<<dim3(1024 / 32, 1280 / 32), dim3(32, 8), 0, stream>>>(
      W_cu, (unsigned short*)(ws + OFF_WTCU), KCU, 1024);
  transpose_to_bf16<<<dim3(1024 / 32, 2304 / 32), dim3(32, 8), 0, stream>>>(
      W_h, (unsigned short*)(ws + OFF_WTH), KFI, 1024);
  transpose_to_bf16<<<dim3(128 / 32, 1024 / 32), dim3(32, 8), 0, stream>>>(
      W_out, (unsigned short*)(ws + OFF_WTOUT), N_, 128);

  embed_kernel<<<T_ * B_, NE_, 0, stream>>>(x, emb, (unsigned short*)(ws + OFF_XE));

  zero_sync_region<<<516, 256, 0, stream>>>(ws);  /* flags + cbf */
  zero_h0<<<128, 256, 0, stream>>>(ws);           /* h slot 0 per batch row */

  char* wsp = ws;
  void* kargs[4] = { (void*)&wsp, (void*)&b_fi, (void*)&b_cu, (void*)&b_h };
  hipLaunchCooperativeKernel((void*)lstm_persistent, dim3(256), dim3(256),
                             kargs, 0, stream);

  out_gemm<<<(B_ * T_) / 32, 256, 0, stream>>>(ws, b_out, y);
}